// Round 9
// baseline (77.535 us; speedup 1.0000x reference)
//
#include <hip/hip_runtime.h>

// Problem constants (match reference setup_inputs()).
#define NUM_ENTITIES 100000
#define NUM_RELATIONS 256

// Range-partitioned LDS privatization, templated so we can pick the config
// by available ws at launch.
//   Config A: RANGES=6, RSIZE=16668 (~68 KB LDS) -> 2 blocks/CU, 32 waves/CU.
//   Config B: RANGES=4, RSIZE=25000 (~101 KB LDS) -> 1 block/CU, 16 waves/CU.
// Block mapping is range-major; CHUNKS % 8 == 0 so the RANGES siblings of a
// chunk land on the SAME XCD under round-robin dispatch and share its L2 for
// the chunk's index stream. Edge loop is 2x-unrolled: both iterations' int4
// streaming loads are issued before either chain consumes (ILP for the
// latency-bound gather/atomic chains).
template <int RANGES, int RSIZE, int CHUNKS, int BLOCK>
__global__ __launch_bounds__(BLOCK) void mp_range_kernel_t(
    const int* __restrict__ row,     // [nnz]
    const int* __restrict__ col,     // [nnz]
    const int* __restrict__ mask,    // [nnz]
    const float* __restrict__ e,     // [E]
    const float* __restrict__ p,     // [R]
    float* __restrict__ ws,          // [RANGES * CHUNKS * RSIZE]
    int nnz)
{
    __shared__ float acc[RSIZE];
    __shared__ float p_lds[NUM_RELATIONS];

    if (threadIdx.x < NUM_RELATIONS) p_lds[threadIdx.x] = p[threadIdx.x];
    {   // zero LDS accumulator (vectorized; RSIZE % 4 == 0)
        float4* a4 = reinterpret_cast<float4*>(acc);
        const float4 z = {0.f, 0.f, 0.f, 0.f};
        for (int i = threadIdx.x; i < RSIZE / 4; i += BLOCK) a4[i] = z;
    }
    __syncthreads();

    const int range = blockIdx.x / CHUNKS;   // compile-time divisor
    const int chunk = blockIdx.x % CHUNKS;
    const int base  = range * RSIZE;

    const int nvec      = nnz >> 2;
    const int per_chunk = (nvec + CHUNKS - 1) / CHUNKS;
    const int v_lo      = chunk * per_chunk;
    const int v_hi      = min(v_lo + per_chunk, nvec);

    const int4* __restrict__ row4  = reinterpret_cast<const int4*>(row);
    const int4* __restrict__ col4  = reinterpret_cast<const int4*>(col);
    const int4* __restrict__ mask4 = reinterpret_cast<const int4*>(mask);

    for (int v = v_lo + (int)threadIdx.x; v < v_hi; v += 2 * BLOCK) {
        const int v2  = v + BLOCK;
        const bool b2 = v2 < v_hi;

        // Issue all streaming loads up front (two independent chains).
        int4 c4a = col4[v];
        int4 r4a = row4[v];
        int4 m4a = mask4[v];
        int4 c4b, r4b, m4b;
        if (b2) {
            c4b = col4[v2];
            r4b = row4[v2];
            m4b = mask4[v2];
        }

        // Chain A
        {
            int o0 = (int)((unsigned)c4a.x % NUM_ENTITIES) - base;
            int o1 = (int)((unsigned)c4a.y % NUM_ENTITIES) - base;
            int o2 = (int)((unsigned)c4a.z % NUM_ENTITIES) - base;
            int o3 = (int)((unsigned)c4a.w % NUM_ENTITIES) - base;
            if ((unsigned)o0 < RSIZE) atomicAdd(&acc[o0], p_lds[m4a.x] * e[r4a.x]);
            if ((unsigned)o1 < RSIZE) atomicAdd(&acc[o1], p_lds[m4a.y] * e[r4a.y]);
            if ((unsigned)o2 < RSIZE) atomicAdd(&acc[o2], p_lds[m4a.z] * e[r4a.z]);
            if ((unsigned)o3 < RSIZE) atomicAdd(&acc[o3], p_lds[m4a.w] * e[r4a.w]);
        }
        // Chain B
        if (b2) {
            int o0 = (int)((unsigned)c4b.x % NUM_ENTITIES) - base;
            int o1 = (int)((unsigned)c4b.y % NUM_ENTITIES) - base;
            int o2 = (int)((unsigned)c4b.z % NUM_ENTITIES) - base;
            int o3 = (int)((unsigned)c4b.w % NUM_ENTITIES) - base;
            if ((unsigned)o0 < RSIZE) atomicAdd(&acc[o0], p_lds[m4b.x] * e[r4b.x]);
            if ((unsigned)o1 < RSIZE) atomicAdd(&acc[o1], p_lds[m4b.y] * e[r4b.y]);
            if ((unsigned)o2 < RSIZE) atomicAdd(&acc[o2], p_lds[m4b.z] * e[r4b.z]);
            if ((unsigned)o3 < RSIZE) atomicAdd(&acc[o3], p_lds[m4b.w] * e[r4b.w]);
        }
    }

    // Scalar tail (nnz not divisible by 4) — handled once per range.
    if (chunk == 0) {
        for (int i = (nvec << 2) + (int)threadIdx.x; i < nnz; i += BLOCK) {
            int o = (int)((unsigned)col[i] % NUM_ENTITIES) - base;
            if ((unsigned)o < RSIZE) atomicAdd(&acc[o], p_lds[mask[i]] * e[row[i]]);
        }
    }

    __syncthreads();

    // Flush full partial (writes everything -> ws needs no pre-zeroing).
    float4* __restrict__ dst =
        reinterpret_cast<float4*>(ws + ((size_t)range * CHUNKS + chunk) * RSIZE);
    const float4* a4 = reinterpret_cast<const float4*>(acc);
    for (int i = threadIdx.x; i < RSIZE / 4; i += BLOCK) dst[i] = a4[i];
}

// Phase 2: out[r*RSIZE + o] = sum over chunks c. Guard for RANGES*RSIZE > E
// (last range partially covers); E % 4 == 0 and RSIZE % 4 == 0 keep float4
// stores aligned and entirely in-range whenever their base is.
template <int RANGES, int RSIZE, int CHUNKS>
__global__ __launch_bounds__(256) void mp_reduce_kernel_t(
    const float* __restrict__ ws,
    float* __restrict__ out)
{
    const int nv4r      = RSIZE / 4;
    const int nv4_total = nv4r * RANGES;
    int i = blockIdx.x * blockDim.x + threadIdx.x;
    if (i >= nv4_total) return;
    int r  = i / nv4r;
    int ov = i - r * nv4r;
    int G  = r * RSIZE + ov * 4;          // global float index of this float4
    if (G >= NUM_ENTITIES) return;        // past-end slice of last range

    const float4* __restrict__ ws4 = reinterpret_cast<const float4*>(ws);
    size_t rbase = (size_t)r * CHUNKS * nv4r;
    float4 s = ws4[rbase + ov];
    #pragma unroll 8
    for (int c = 1; c < CHUNKS; ++c) {
        float4 t = ws4[rbase + (size_t)c * nv4r + ov];
        s.x += t.x; s.y += t.y; s.z += t.z; s.w += t.w;
    }
    *reinterpret_cast<float4*>(out + G) = s;
}

// Fallback (ws unexpectedly tiny): direct device-scope atomics (slow, correct).
__global__ __launch_bounds__(256) void mp_scatter_direct_kernel(
    const int* __restrict__ row, const int* __restrict__ col,
    const int* __restrict__ mask, const float* __restrict__ e,
    const float* __restrict__ p, float* __restrict__ out, int nnz)
{
    __shared__ float p_lds[NUM_RELATIONS];
    if (threadIdx.x < NUM_RELATIONS) p_lds[threadIdx.x] = p[threadIdx.x];
    __syncthreads();
    const int tid    = blockIdx.x * blockDim.x + threadIdx.x;
    const int stride = gridDim.x * blockDim.x;
    for (int i = tid; i < nnz; i += stride) {
        float v = p_lds[mask[i]] * e[row[i]];
        atomicAdd(&out[(unsigned)col[i] % NUM_ENTITIES], v);
    }
}

extern "C" void kernel_launch(void* const* d_in, const int* in_sizes, int n_in,
                              void* d_out, int out_size, void* d_ws, size_t ws_size,
                              hipStream_t stream) {
    const int*   indices = (const int*)d_in[0];
    const float* e       = (const float*)d_in[1];
    const float* p       = (const float*)d_in[2];
    const int*   mask    = (const int*)d_in[3];

    const int nnz = in_sizes[3];            // 8,000,000
    const int* row = indices;               // indices[0, :]
    const int* col = indices + nnz;         // indices[1, :]
    float* out = (float*)d_out;
    float* ws  = (float*)d_ws;

    // Config A: 6 ranges, ~68 KB LDS -> 2 blocks/CU (32 waves/CU).
    constexpr int RA = 6, RSA = 16668, CA = 80, BA = 1024;
    // Config B: 4 ranges, ~101 KB LDS -> 1 block/CU (16 waves/CU).
    constexpr int RB = 4, RSB = 25000, CB = 64, BB = 1024;

    const size_t needA = (size_t)RA * CA * RSA * sizeof(float); // 32.0 MB
    const size_t needB = (size_t)RB * CB * RSB * sizeof(float); // 25.6 MB

    if (ws_size >= needA) {
        mp_range_kernel_t<RA, RSA, CA, BA><<<RA * CA, BA, 0, stream>>>(
            row, col, mask, e, p, ws, nnz);
        const int nv4_total = (RSA / 4) * RA;  // 25002
        mp_reduce_kernel_t<RA, RSA, CA><<<(nv4_total + 255) / 256, 256, 0, stream>>>(
            ws, out);
    } else if (ws_size >= needB) {
        mp_range_kernel_t<RB, RSB, CB, BB><<<RB * CB, BB, 0, stream>>>(
            row, col, mask, e, p, ws, nnz);
        const int nv4_total = (RSB / 4) * RB;  // 25000
        mp_reduce_kernel_t<RB, RSB, CB><<<(nv4_total + 255) / 256, 256, 0, stream>>>(
            ws, out);
    } else {
        hipMemsetAsync(out, 0, (size_t)out_size * sizeof(float), stream);
        mp_scatter_direct_kernel<<<2048, 256, 0, stream>>>(row, col, mask, e, p, out, nnz);
    }
}

// Round 10
// 74.480 us; speedup vs baseline: 1.0410x; 1.0410x over previous
//
#include <hip/hip_runtime.h>

// Problem constants (match reference setup_inputs()).
#define NUM_ENTITIES 100000
#define NUM_RELATIONS 256

// Range-partitioned LDS privatization, templated; config picked by ws size.
//   Config C: RANGES=3, RSIZE=33336 (~134 KB LDS) -> 1 block/CU, 16 waves/CU,
//             3 scan passes (25% less scan work than config B).
//   Config B: RANGES=4, RSIZE=25000 (~101 KB LDS) -> 1 block/CU, 16 waves/CU.
// Block mapping is range-major; CHUNKS % 8 == 0 so the RANGES siblings of a
// chunk land on the SAME XCD under round-robin dispatch and share its L2 for
// the chunk's index stream. Edge loop is 2x-unrolled (two independent
// load->gather->ds_add chains in flight per wave).
template <int RANGES, int RSIZE, int CHUNKS, int BLOCK>
__global__ __launch_bounds__(BLOCK) void mp_range_kernel_t(
    const int* __restrict__ row,     // [nnz]
    const int* __restrict__ col,     // [nnz]
    const int* __restrict__ mask,    // [nnz]
    const float* __restrict__ e,     // [E]
    const float* __restrict__ p,     // [R]
    float* __restrict__ ws,          // [RANGES * CHUNKS * RSIZE]
    int nnz)
{
    __shared__ float acc[RSIZE];
    __shared__ float p_lds[NUM_RELATIONS];

    if (threadIdx.x < NUM_RELATIONS) p_lds[threadIdx.x] = p[threadIdx.x];
    {   // zero LDS accumulator (vectorized; RSIZE % 4 == 0)
        float4* a4 = reinterpret_cast<float4*>(acc);
        const float4 z = {0.f, 0.f, 0.f, 0.f};
        for (int i = threadIdx.x; i < RSIZE / 4; i += BLOCK) a4[i] = z;
    }
    __syncthreads();

    const int range = blockIdx.x / CHUNKS;   // compile-time divisor
    const int chunk = blockIdx.x % CHUNKS;
    const int base  = range * RSIZE;

    const int nvec      = nnz >> 2;
    const int per_chunk = (nvec + CHUNKS - 1) / CHUNKS;
    const int v_lo      = chunk * per_chunk;
    const int v_hi      = min(v_lo + per_chunk, nvec);

    const int4* __restrict__ row4  = reinterpret_cast<const int4*>(row);
    const int4* __restrict__ col4  = reinterpret_cast<const int4*>(col);
    const int4* __restrict__ mask4 = reinterpret_cast<const int4*>(mask);

    for (int v = v_lo + (int)threadIdx.x; v < v_hi; v += 2 * BLOCK) {
        const int v2  = v + BLOCK;
        const bool b2 = v2 < v_hi;

        // Issue all streaming loads up front (two independent chains).
        int4 c4a = col4[v];
        int4 r4a = row4[v];
        int4 m4a = mask4[v];
        int4 c4b, r4b, m4b;
        if (b2) {
            c4b = col4[v2];
            r4b = row4[v2];
            m4b = mask4[v2];
        }

        // Chain A
        {
            int o0 = (int)((unsigned)c4a.x % NUM_ENTITIES) - base;
            int o1 = (int)((unsigned)c4a.y % NUM_ENTITIES) - base;
            int o2 = (int)((unsigned)c4a.z % NUM_ENTITIES) - base;
            int o3 = (int)((unsigned)c4a.w % NUM_ENTITIES) - base;
            if ((unsigned)o0 < RSIZE) atomicAdd(&acc[o0], p_lds[m4a.x] * e[r4a.x]);
            if ((unsigned)o1 < RSIZE) atomicAdd(&acc[o1], p_lds[m4a.y] * e[r4a.y]);
            if ((unsigned)o2 < RSIZE) atomicAdd(&acc[o2], p_lds[m4a.z] * e[r4a.z]);
            if ((unsigned)o3 < RSIZE) atomicAdd(&acc[o3], p_lds[m4a.w] * e[r4a.w]);
        }
        // Chain B
        if (b2) {
            int o0 = (int)((unsigned)c4b.x % NUM_ENTITIES) - base;
            int o1 = (int)((unsigned)c4b.y % NUM_ENTITIES) - base;
            int o2 = (int)((unsigned)c4b.z % NUM_ENTITIES) - base;
            int o3 = (int)((unsigned)c4b.w % NUM_ENTITIES) - base;
            if ((unsigned)o0 < RSIZE) atomicAdd(&acc[o0], p_lds[m4b.x] * e[r4b.x]);
            if ((unsigned)o1 < RSIZE) atomicAdd(&acc[o1], p_lds[m4b.y] * e[r4b.y]);
            if ((unsigned)o2 < RSIZE) atomicAdd(&acc[o2], p_lds[m4b.z] * e[r4b.z]);
            if ((unsigned)o3 < RSIZE) atomicAdd(&acc[o3], p_lds[m4b.w] * e[r4b.w]);
        }
    }

    // Scalar tail (nnz not divisible by 4) — handled once per range.
    if (chunk == 0) {
        for (int i = (nvec << 2) + (int)threadIdx.x; i < nnz; i += BLOCK) {
            int o = (int)((unsigned)col[i] % NUM_ENTITIES) - base;
            if ((unsigned)o < RSIZE) atomicAdd(&acc[o], p_lds[mask[i]] * e[row[i]]);
        }
    }

    __syncthreads();

    // Flush full partial (writes everything -> ws needs no pre-zeroing).
    float4* __restrict__ dst =
        reinterpret_cast<float4*>(ws + ((size_t)range * CHUNKS + chunk) * RSIZE);
    const float4* a4 = reinterpret_cast<const float4*>(acc);
    for (int i = threadIdx.x; i < RSIZE / 4; i += BLOCK) dst[i] = a4[i];
}

// Phase 2: out[r*RSIZE + o] = sum over chunks c. Guard for RANGES*RSIZE > E
// (last range partially covers); E % 4 == 0 and RSIZE % 4 == 0 keep float4
// stores aligned and entirely in-range whenever their base is.
template <int RANGES, int RSIZE, int CHUNKS>
__global__ __launch_bounds__(256) void mp_reduce_kernel_t(
    const float* __restrict__ ws,
    float* __restrict__ out)
{
    const int nv4r      = RSIZE / 4;
    const int nv4_total = nv4r * RANGES;
    int i = blockIdx.x * blockDim.x + threadIdx.x;
    if (i >= nv4_total) return;
    int r  = i / nv4r;
    int ov = i - r * nv4r;
    int G  = r * RSIZE + ov * 4;          // global float index of this float4
    if (G >= NUM_ENTITIES) return;        // past-end slice of last range

    const float4* __restrict__ ws4 = reinterpret_cast<const float4*>(ws);
    size_t rbase = (size_t)r * CHUNKS * nv4r;
    float4 s = ws4[rbase + ov];
    #pragma unroll 8
    for (int c = 1; c < CHUNKS; ++c) {
        float4 t = ws4[rbase + (size_t)c * nv4r + ov];
        s.x += t.x; s.y += t.y; s.z += t.z; s.w += t.w;
    }
    *reinterpret_cast<float4*>(out + G) = s;
}

// Fallback (ws unexpectedly tiny): direct device-scope atomics (slow, correct).
__global__ __launch_bounds__(256) void mp_scatter_direct_kernel(
    const int* __restrict__ row, const int* __restrict__ col,
    const int* __restrict__ mask, const float* __restrict__ e,
    const float* __restrict__ p, float* __restrict__ out, int nnz)
{
    __shared__ float p_lds[NUM_RELATIONS];
    if (threadIdx.x < NUM_RELATIONS) p_lds[threadIdx.x] = p[threadIdx.x];
    __syncthreads();
    const int tid    = blockIdx.x * blockDim.x + threadIdx.x;
    const int stride = gridDim.x * blockDim.x;
    for (int i = tid; i < nnz; i += stride) {
        float v = p_lds[mask[i]] * e[row[i]];
        atomicAdd(&out[(unsigned)col[i] % NUM_ENTITIES], v);
    }
}

extern "C" void kernel_launch(void* const* d_in, const int* in_sizes, int n_in,
                              void* d_out, int out_size, void* d_ws, size_t ws_size,
                              hipStream_t stream) {
    const int*   indices = (const int*)d_in[0];
    const float* e       = (const float*)d_in[1];
    const float* p       = (const float*)d_in[2];
    const int*   mask    = (const int*)d_in[3];

    const int nnz = in_sizes[3];            // 8,000,000
    const int* row = indices;               // indices[0, :]
    const int* col = indices + nnz;         // indices[1, :]
    float* out = (float*)d_out;
    float* ws  = (float*)d_ws;

    // Config C: 3 ranges, ~134 KB LDS -> 16 waves/CU, 3 scan passes.
    constexpr int RC = 3, RSC = 33336, CC = 72, BC = 1024;
    // Config B: 4 ranges, ~101 KB LDS -> 16 waves/CU, 4 scan passes.
    constexpr int RB = 4, RSB = 25000, CB = 64, BB = 1024;

    const size_t needC = (size_t)RC * CC * RSC * sizeof(float); // 28.8 MB
    const size_t needB = (size_t)RB * CB * RSB * sizeof(float); // 25.6 MB

    if (ws_size >= needC) {
        mp_range_kernel_t<RC, RSC, CC, BC><<<RC * CC, BC, 0, stream>>>(
            row, col, mask, e, p, ws, nnz);
        const int nv4_total = (RSC / 4) * RC;  // 25002
        mp_reduce_kernel_t<RC, RSC, CC><<<(nv4_total + 255) / 256, 256, 0, stream>>>(
            ws, out);
    } else if (ws_size >= needB) {
        mp_range_kernel_t<RB, RSB, CB, BB><<<RB * CB, BB, 0, stream>>>(
            row, col, mask, e, p, ws, nnz);
        const int nv4_total = (RSB / 4) * RB;  // 25000
        mp_reduce_kernel_t<RB, RSB, CB><<<(nv4_total + 255) / 256, 256, 0, stream>>>(
            ws, out);
    } else {
        hipMemsetAsync(out, 0, (size_t)out_size * sizeof(float), stream);
        mp_scatter_direct_kernel<<<2048, 256, 0, stream>>>(row, col, mask, e, p, out, nnz);
    }
}

// Round 11
// 70.943 us; speedup vs baseline: 1.0929x; 1.0499x over previous
//
#include <hip/hip_runtime.h>

// Problem constants (match reference setup_inputs()).
#define NUM_ENTITIES 100000
#define NUM_RELATIONS 256

// Range-partitioned LDS privatization. Config B proved equal-best across
// {RANGES,occupancy} sweeps (rounds 7-10): the limiter is per-lane random
// gather/atomic throughput, invariant to passes and waves. This round: 4
// independent load->gather->ds_add chains per wave (16 outstanding gathers
// per thread) to squeeze the residual latency component (round 8: 2 chains
// gave +8%).
template <int RANGES, int RSIZE, int CHUNKS, int BLOCK>
__global__ __launch_bounds__(BLOCK) void mp_range_kernel_t(
    const int* __restrict__ row,     // [nnz]
    const int* __restrict__ col,     // [nnz]
    const int* __restrict__ mask,    // [nnz]
    const float* __restrict__ e,     // [E]
    const float* __restrict__ p,     // [R]
    float* __restrict__ ws,          // [RANGES * CHUNKS * RSIZE]
    int nnz)
{
    __shared__ float acc[RSIZE];
    __shared__ float p_lds[NUM_RELATIONS];

    if (threadIdx.x < NUM_RELATIONS) p_lds[threadIdx.x] = p[threadIdx.x];
    {   // zero LDS accumulator (vectorized; RSIZE % 4 == 0)
        float4* a4 = reinterpret_cast<float4*>(acc);
        const float4 z = {0.f, 0.f, 0.f, 0.f};
        for (int i = threadIdx.x; i < RSIZE / 4; i += BLOCK) a4[i] = z;
    }
    __syncthreads();

    const int range = blockIdx.x / CHUNKS;   // compile-time divisor
    const int chunk = blockIdx.x % CHUNKS;
    const int base  = range * RSIZE;

    const int nvec      = nnz >> 2;
    const int per_chunk = (nvec + CHUNKS - 1) / CHUNKS;
    const int v_lo      = chunk * per_chunk;
    const int v_hi      = min(v_lo + per_chunk, nvec);

    const int4* __restrict__ row4  = reinterpret_cast<const int4*>(row);
    const int4* __restrict__ col4  = reinterpret_cast<const int4*>(col);
    const int4* __restrict__ mask4 = reinterpret_cast<const int4*>(mask);

    auto proc = [&](int4 c4, int4 r4, int4 m4) {
        int o0 = (int)((unsigned)c4.x % NUM_ENTITIES) - base;
        int o1 = (int)((unsigned)c4.y % NUM_ENTITIES) - base;
        int o2 = (int)((unsigned)c4.z % NUM_ENTITIES) - base;
        int o3 = (int)((unsigned)c4.w % NUM_ENTITIES) - base;
        if ((unsigned)o0 < RSIZE) atomicAdd(&acc[o0], p_lds[m4.x] * e[r4.x]);
        if ((unsigned)o1 < RSIZE) atomicAdd(&acc[o1], p_lds[m4.y] * e[r4.y]);
        if ((unsigned)o2 < RSIZE) atomicAdd(&acc[o2], p_lds[m4.z] * e[r4.z]);
        if ((unsigned)o3 < RSIZE) atomicAdd(&acc[o3], p_lds[m4.w] * e[r4.w]);
    };

    for (int v = v_lo + (int)threadIdx.x; v < v_hi; v += 4 * BLOCK) {
        const int vB = v + BLOCK, vC = v + 2 * BLOCK, vD = v + 3 * BLOCK;
        const bool bB = vB < v_hi, bC = vC < v_hi, bD = vD < v_hi;

        // Issue all streaming loads up front (four independent chains).
        int4 cA = col4[v], rA = row4[v], mA = mask4[v];
        int4 cB, rB, mB, cC, rC, mC, cD, rD, mD;
        if (bB) { cB = col4[vB]; rB = row4[vB]; mB = mask4[vB]; }
        if (bC) { cC = col4[vC]; rC = row4[vC]; mC = mask4[vC]; }
        if (bD) { cD = col4[vD]; rD = row4[vD]; mD = mask4[vD]; }

        proc(cA, rA, mA);
        if (bB) proc(cB, rB, mB);
        if (bC) proc(cC, rC, mC);
        if (bD) proc(cD, rD, mD);
    }

    // Scalar tail (nnz not divisible by 4) — handled once per range.
    if (chunk == 0) {
        for (int i = (nvec << 2) + (int)threadIdx.x; i < nnz; i += BLOCK) {
            int o = (int)((unsigned)col[i] % NUM_ENTITIES) - base;
            if ((unsigned)o < RSIZE) atomicAdd(&acc[o], p_lds[mask[i]] * e[row[i]]);
        }
    }

    __syncthreads();

    // Flush full partial (writes everything -> ws needs no pre-zeroing).
    float4* __restrict__ dst =
        reinterpret_cast<float4*>(ws + ((size_t)range * CHUNKS + chunk) * RSIZE);
    const float4* a4 = reinterpret_cast<const float4*>(acc);
    for (int i = threadIdx.x; i < RSIZE / 4; i += BLOCK) dst[i] = a4[i];
}

// Phase 2: out[r*RSIZE + o] = sum over chunks c. Guard for RANGES*RSIZE > E.
template <int RANGES, int RSIZE, int CHUNKS>
__global__ __launch_bounds__(256) void mp_reduce_kernel_t(
    const float* __restrict__ ws,
    float* __restrict__ out)
{
    const int nv4r      = RSIZE / 4;
    const int nv4_total = nv4r * RANGES;
    int i = blockIdx.x * blockDim.x + threadIdx.x;
    if (i >= nv4_total) return;
    int r  = i / nv4r;
    int ov = i - r * nv4r;
    int G  = r * RSIZE + ov * 4;          // global float index of this float4
    if (G >= NUM_ENTITIES) return;        // past-end slice of last range

    const float4* __restrict__ ws4 = reinterpret_cast<const float4*>(ws);
    size_t rbase = (size_t)r * CHUNKS * nv4r;
    float4 s = ws4[rbase + ov];
    #pragma unroll 8
    for (int c = 1; c < CHUNKS; ++c) {
        float4 t = ws4[rbase + (size_t)c * nv4r + ov];
        s.x += t.x; s.y += t.y; s.z += t.z; s.w += t.w;
    }
    *reinterpret_cast<float4*>(out + G) = s;
}

// Fallback (ws unexpectedly tiny): direct device-scope atomics (slow, correct).
__global__ __launch_bounds__(256) void mp_scatter_direct_kernel(
    const int* __restrict__ row, const int* __restrict__ col,
    const int* __restrict__ mask, const float* __restrict__ e,
    const float* __restrict__ p, float* __restrict__ out, int nnz)
{
    __shared__ float p_lds[NUM_RELATIONS];
    if (threadIdx.x < NUM_RELATIONS) p_lds[threadIdx.x] = p[threadIdx.x];
    __syncthreads();
    const int tid    = blockIdx.x * blockDim.x + threadIdx.x;
    const int stride = gridDim.x * blockDim.x;
    for (int i = tid; i < nnz; i += stride) {
        float v = p_lds[mask[i]] * e[row[i]];
        atomicAdd(&out[(unsigned)col[i] % NUM_ENTITIES], v);
    }
}

extern "C" void kernel_launch(void* const* d_in, const int* in_sizes, int n_in,
                              void* d_out, int out_size, void* d_ws, size_t ws_size,
                              hipStream_t stream) {
    const int*   indices = (const int*)d_in[0];
    const float* e       = (const float*)d_in[1];
    const float* p       = (const float*)d_in[2];
    const int*   mask    = (const int*)d_in[3];

    const int nnz = in_sizes[3];            // 8,000,000
    const int* row = indices;               // indices[0, :]
    const int* col = indices + nnz;         // indices[1, :]
    float* out = (float*)d_out;
    float* ws  = (float*)d_ws;

    // Config B: 4 ranges, ~101 KB LDS -> 1 block/CU, 16 waves/CU.
    constexpr int RB = 4, RSB = 25000, CB = 64, BB = 1024;
    const size_t needB = (size_t)RB * CB * RSB * sizeof(float); // 25.6 MB

    if (ws_size >= needB) {
        mp_range_kernel_t<RB, RSB, CB, BB><<<RB * CB, BB, 0, stream>>>(
            row, col, mask, e, p, ws, nnz);
        const int nv4_total = (RSB / 4) * RB;  // 25000
        mp_reduce_kernel_t<RB, RSB, CB><<<(nv4_total + 255) / 256, 256, 0, stream>>>(
            ws, out);
    } else {
        hipMemsetAsync(out, 0, (size_t)out_size * sizeof(float), stream);
        mp_scatter_direct_kernel<<<2048, 256, 0, stream>>>(row, col, mask, e, p, out, nnz);
    }
}